// Round 21
// baseline (86.691 us; speedup 1.0000x reference)
//
#include <hip/hip_runtime.h>
#include <hip/hip_bf16.h>

#define NROWS 2048
#define L2E 1.4426950408889634f

typedef float f32x4 __attribute__((ext_vector_type(4)));
typedef __bf16 bf16x8 __attribute__((ext_vector_type(8)));
typedef short s16x8 __attribute__((ext_vector_type(8)));

typedef const __attribute__((address_space(1))) unsigned int* gas_t;
typedef __attribute__((address_space(3))) unsigned int* las_t;

__device__ __forceinline__ unsigned short f2bf(float f) {
    unsigned int u = __float_as_uint(f);
    unsigned int r = (u + 0x7FFFu + ((u >> 16) & 1u)) >> 16;
    return (unsigned short)r;
}
__device__ __forceinline__ float bf2f(unsigned short u) {
    return __uint_as_float((unsigned int)u << 16);
}
__device__ __forceinline__ f32x4 mfma16(s16x8 a, s16x8 b, f32x4 c) {
    return __builtin_amdgcn_mfma_f32_16x16x32_bf16(
        __builtin_bit_cast(bf16x8, a), __builtin_bit_cast(bf16x8, b), c, 0, 0, 0);
}

// ---------------- merged prologue: gather x | convert weights | prep ----------------
__global__ void k_prologue(const float* __restrict__ lhs, const int* __restrict__ idx,
                           const float* __restrict__ hw, const float* __restrict__ p0w,
                           const float* __restrict__ p1w, const float* __restrict__ o0w,
                           const float* __restrict__ o1w, const float* __restrict__ hb,
                           const int* __restrict__ tgt,
                           unsigned short* __restrict__ xb, unsigned short* __restrict__ hWb,
                           unsigned short* __restrict__ pW01, unsigned short* __restrict__ o0Wb,
                           unsigned short* __restrict__ o1Wb,
                           float* __restrict__ bias_s, int* __restrict__ tc,
                           unsigned long long* __restrict__ lossacc,
                           unsigned int* __restrict__ ticket) {
    int bid = blockIdx.x;
    if (bid < 2048) {                      // ---- gather x: 2048 rows x 1024 cols bf16
        int tid = bid * 256 + threadIdx.x;
        int n = tid >> 8;
        int c = (tid & 255) << 2;
        int b = n >> 8, k = n & 255;
        int srow = idx[(b << 8) + k];
        const float4 v = *reinterpret_cast<const float4*>(
            lhs + (((size_t)b << 9) + srow) * 1024 + c);
        ushort4 o = make_ushort4(f2bf(v.x), f2bf(v.y), f2bf(v.z), f2bf(v.w));
        *reinterpret_cast<ushort4*>(xb + (size_t)n * 1024 + c) = o;
        return;
    }
    bid -= 2048;
    if (bid < 6968) {                      // ---- weight conversion (exp-weights * log2e)
        const long B0 = 2048L * 1024;
        const long B1 = B0 + 384L * 1024;
        const long B2 = B1 + 8064L * 256;
        const long B3 = B2 + 40320L * 64;
        long e = ((long)bid * 256 + threadIdx.x) * 4;
        if (e >= B3) return;
        const float* src; unsigned short* dst; long rows; int colshift; long base;
        float sc;
        if (e < B0)      { base = 0;  src = hw;  dst = hWb;  rows = 2002;  colshift = 10; sc = L2E; }
        else if (e < B1) {
            long l = e - B0;
            long row = l >> 10;
            unsigned short* d = pW01 + l;
            ushort4 o;
            if (row < 256) {
                float4 v = *reinterpret_cast<const float4*>(p0w + l);
                o = make_ushort4(f2bf(v.x), f2bf(v.y), f2bf(v.z), f2bf(v.w));
            } else if (row < 320) {
                float4 v = *reinterpret_cast<const float4*>(p1w + (l - 256L * 1024));
                o = make_ushort4(f2bf(v.x), f2bf(v.y), f2bf(v.z), f2bf(v.w));
            } else {
                o = make_ushort4(0, 0, 0, 0);
            }
            *reinterpret_cast<ushort4*>(d) = o;
            return;
        }
        else if (e < B2) { base = B1; src = o0w; dst = o0Wb; rows = 8000;  colshift = 8; sc = L2E; }
        else             { base = B2; src = o1w; dst = o1Wb; rows = 40257; colshift = 6; sc = L2E; }
        long l = e - base;
        long row = l >> colshift;
        ushort4 o;
        if (row < rows) {
            float4 v = *reinterpret_cast<const float4*>(src + l);
            o = make_ushort4(f2bf(v.x * sc), f2bf(v.y * sc), f2bf(v.z * sc), f2bf(v.w * sc));
        } else {
            o = make_ushort4(0, 0, 0, 0);
        }
        *reinterpret_cast<ushort4*>(dst + l) = o;
        return;
    }
    bid -= 6968;                           // ---- prep (8 blocks)
    int n = bid * 256 + threadIdx.x;
    if (n >= 2048) return;
    if (n == 0) { *lossacc = 0ull; *ticket = 0u; }
    bias_s[n] = (n < 2002) ? hb[n] * L2E : -1e30f;
    int t = tgt[n];
    tc[n] = min(t, 1999);
    tc[2048 + n] = min(max(t - 2000, 0), 7999);
    tc[4096 + n] = min(max(t - 10000, 0), 40256);
}

// ------- head+proj: 64x128-tile GEMM, BK=64, dbuf + XOR swizzle, XCD-swizzled -------
template <int NT>
__global__ __launch_bounds__(256)
void k_mm(const unsigned short* __restrict__ A, int lda,
          const unsigned short* __restrict__ B, int ldb,
          const float* __restrict__ bias, float* __restrict__ partial,
          unsigned short* __restrict__ hout, int hstride, int hcols, int fsplit) {
    __shared__ unsigned short As[2][64 * 64];
    __shared__ unsigned short Bs[2][128 * 64];
    const int tid = threadIdx.x;
    const int lane = tid & 63, wid = tid >> 6;
    const int wc = wid;
    const int g = lane >> 4, cl = lane & 15;
    int raw = (int)blockIdx.x;
    int bid = (raw & 7) * 76 + (raw >> 3);           // XCD swizzle (608 = 8*76)
    const int bx = bid & 31, by = bid >> 5;
    const int row0 = bx * 64;
    const int col0 = by * 128;

    const int sr = wid * 8 + (lane >> 3);
    const int swz = ((lane & 7) ^ (lane >> 3)) * 8;
    const unsigned short* Ab = A + (size_t)(row0 + sr) * lda + swz;
    const unsigned short* Bb = B + (size_t)(col0 + sr) * ldb + swz;

    auto stage = [&](int buf, int kt) {
        unsigned short* la = &As[buf][wid * 8 * 64];
        unsigned short* lb = &Bs[buf][wid * 8 * 64];
#pragma unroll
        for (int i = 0; i < 2; ++i)
            __builtin_amdgcn_global_load_lds((gas_t)(const void*)(Ab + kt + (size_t)i * 32 * lda),
                                             (las_t)(void*)(la + i * 32 * 64), 16, 0, 0);
#pragma unroll
        for (int i = 0; i < 4; ++i)
            __builtin_amdgcn_global_load_lds((gas_t)(const void*)(Bb + kt + (size_t)i * 32 * ldb),
                                             (las_t)(void*)(lb + i * 32 * 64), 16, 0, 0);
    };

    f32x4 acc[4][2] = {};
    stage(0, 0);
    asm volatile("s_waitcnt vmcnt(0)" ::: "memory");
    __builtin_amdgcn_s_barrier();
    const int sA = (cl & 7);
    for (int t = 0; t < NT; ++t) {
        if (t + 1 < NT) stage((t + 1) & 1, (t + 1) * 64);
        const unsigned short* Al = &As[t & 1][cl * 64];
        const unsigned short* Bl = &Bs[t & 1][(wc * 32 + cl) * 64];
#pragma unroll
        for (int kk2 = 0; kk2 < 2; ++kk2) {
            const int slot = ((kk2 * 4 + g) ^ sA) * 8;
            s16x8 a[4], b[2];
#pragma unroll
            for (int mi = 0; mi < 4; ++mi)
                a[mi] = *reinterpret_cast<const s16x8*>(Al + mi * 16 * 64 + slot);
#pragma unroll
            for (int ni = 0; ni < 2; ++ni)
                b[ni] = *reinterpret_cast<const s16x8*>(Bl + ni * 16 * 64 + slot);
#pragma unroll
            for (int mi = 0; mi < 4; ++mi)
#pragma unroll
                for (int ni = 0; ni < 2; ++ni)
                    acc[mi][ni] = mfma16(a[mi], b[ni], acc[mi][ni]);
        }
        if (t + 1 < NT) {
            asm volatile("s_waitcnt vmcnt(0)" ::: "memory");
            __builtin_amdgcn_s_barrier();
        }
    }

    if (by >= fsplit) {
        int c0 = col0 - fsplit * 128;
#pragma unroll
        for (int mi = 0; mi < 4; ++mi)
#pragma unroll
            for (int ni = 0; ni < 2; ++ni) {
                int col = c0 + wc * 32 + ni * 16 + cl;
                if (col < hcols) {
#pragma unroll
                    for (int r = 0; r < 4; ++r) {
                        int row = row0 + mi * 16 + g * 4 + r;
                        hout[(size_t)row * hstride + col] = f2bf(acc[mi][ni][r]);
                    }
                }
            }
    } else {
        float bv0 = bias[col0 + wc * 32 + cl];
        float bv1 = bias[col0 + wc * 32 + 16 + cl];
        int strip = by * 4 + wc;
#pragma unroll
        for (int mi = 0; mi < 4; ++mi)
#pragma unroll
            for (int r = 0; r < 4; ++r) {
                float s = __builtin_amdgcn_exp2f(acc[mi][0][r] + bv0)
                        + __builtin_amdgcn_exp2f(acc[mi][1][r] + bv1);
                s += __shfl_xor(s, 1, 64);
                s += __shfl_xor(s, 2, 64);
                s += __shfl_xor(s, 4, 64);
                s += __shfl_xor(s, 8, 64);
                if (cl == 0)
                    partial[(size_t)strip * NROWS + row0 + mi * 16 + g * 4 + r] = s;
            }
    }
}

// --- merged tail: out0 (1008, 128x128) | out1 (1008, 3-buf counted vmcnt) | dots (512) ---
#define OUT1_IT 5
__global__ __launch_bounds__(256)
void k_tail(const unsigned short* __restrict__ h01, const unsigned short* __restrict__ o0Wb,
            const unsigned short* __restrict__ o1Wb, const unsigned short* __restrict__ xb,
            const float* __restrict__ headW, const float* __restrict__ hb,
            const float* __restrict__ o0w, const float* __restrict__ o1w,
            const int* __restrict__ tc,
            float* __restrict__ p0, float* __restrict__ p1,
            float* __restrict__ tgh, float* __restrict__ r0, float* __restrict__ r1,
            float* __restrict__ tg0, float* __restrict__ tg1) {
    __shared__ unsigned short smem[4][128 * 64];
    const int tid = threadIdx.x;
    const int lane = tid & 63, wid = tid >> 6;
    const int wr = wid >> 1, wc = wid & 1;
    const int g = lane >> 4, cl = lane & 15;
    int raw = (int)blockIdx.x;
    int bid;
    if (raw < 1008)      bid = (raw & 7) * 126 + (raw >> 3);
    else if (raw < 2016) { int b = raw - 1008; bid = 1008 + (b & 7) * 126 + (b >> 3); }
    else                 { int b = raw - 2016; bid = 2016 + (b & 7) * 64 + (b >> 3); }

    if (bid < 1008) {
        // ================= out0: 2048 x 8064, K=256, fused exp2-sum =================
        const int row0 = (bid & 15) * 128;
        const int col0 = (bid >> 4) * 128;
        const int sr = wid * 8 + (lane >> 3);
        const int swz = ((lane & 7) ^ (lane >> 3)) * 8;
        const unsigned short* Ab = h01 + (size_t)(row0 + sr) * 320 + swz;
        const unsigned short* Bb = o0Wb + (size_t)(col0 + sr) * 256 + swz;
        auto stage = [&](int buf, int kt) {
            unsigned short* la = &smem[buf][wid * 8 * 64];
            unsigned short* lb = &smem[2 + buf][wid * 8 * 64];
#pragma unroll
            for (int i = 0; i < 4; ++i) {
                __builtin_amdgcn_global_load_lds((gas_t)(const void*)(Ab + kt + (size_t)i * 32 * 320),
                                                 (las_t)(void*)(la + i * 32 * 64), 16, 0, 0);
                __builtin_amdgcn_global_load_lds((gas_t)(const void*)(Bb + kt + (size_t)i * 32 * 256),
                                                 (las_t)(void*)(lb + i * 32 * 64), 16, 0, 0);
            }
        };
        f32x4 acc[4][4] = {};
        stage(0, 0);
        asm volatile("s_waitcnt vmcnt(0)" ::: "memory");
        __builtin_amdgcn_s_barrier();
        const int sA = (cl & 7);
        for (int t = 0; t < 4; ++t) {
            if (t < 3) stage((t + 1) & 1, (t + 1) * 64);
            const unsigned short* Al = &smem[t & 1][(wr * 64 + cl) * 64];
            const unsigned short* Bl = &smem[2 + (t & 1)][(wc * 64 + cl) * 64];
#pragma unroll
            for (int kk2 = 0; kk2 < 2; ++kk2) {
                const int slot = ((kk2 * 4 + g) ^ sA) * 8;
                s16x8 a[4], b[4];
#pragma unroll
                for (int mi = 0; mi < 4; ++mi)
                    a[mi] = *reinterpret_cast<const s16x8*>(Al + mi * 16 * 64 + slot);
#pragma unroll
                for (int ni = 0; ni < 4; ++ni)
                    b[ni] = *reinterpret_cast<const s16x8*>(Bl + ni * 16 * 64 + slot);
#pragma unroll
                for (int mi = 0; mi < 4; ++mi)
#pragma unroll
                    for (int ni = 0; ni < 4; ++ni)
                        acc[mi][ni] = mfma16(a[mi], b[ni], acc[mi][ni]);
            }
            if (t < 3) {
                asm volatile("s_waitcnt vmcnt(0)" ::: "memory");
                __builtin_amdgcn_s_barrier();
            }
        }
        int strip = (bid >> 4) * 2 + wc;
#pragma unroll
        for (int mi = 0; mi < 4; ++mi)
#pragma unroll
            for (int r = 0; r < 4; ++r) {
                float s = 0.f;
#pragma unroll
                for (int ni = 0; ni < 4; ++ni)
                    s += __builtin_amdgcn_exp2f(acc[mi][ni][r]);
                s += __shfl_xor(s, 1, 64);
                s += __shfl_xor(s, 2, 64);
                s += __shfl_xor(s, 4, 64);
                s += __shfl_xor(s, 8, 64);
                if (cl == 0)
                    p0[(size_t)strip * NROWS + row0 + wr * 64 + mi * 16 + g * 4 + r] = s;
            }
        return;
    }
    if (bid < 2016) {
        // ======= out1: 2048 x 40320, K=64, 5 tiles/block, 3-buf counted vmcnt(4) =======
        bid -= 1008;
        const int row0 = (bid & 15) * 128 + wr * 64;
        const int yb = bid >> 4;
        const int t0 = yb * OUT1_IT;
        s16x8 a[4][2];
#pragma unroll
        for (int mi = 0; mi < 4; ++mi)
#pragma unroll
            for (int kk = 0; kk < 2; ++kk)
                a[mi][kk] = *reinterpret_cast<const s16x8*>(
                    h01 + (size_t)(row0 + mi * 16 + cl) * 320 + 256 + kk * 32 + g * 8);
        const int sr = wid * 8 + (lane >> 3);
        const int swz = ((lane & 7) ^ (lane >> 3)) * 8;
        auto stage = [&](int buf, int tile) {
            const unsigned short* gb = o1Wb + ((size_t)tile * 128 + sr) * 64 + swz;
            unsigned short* lb = &smem[buf][wid * 8 * 64];
#pragma unroll
            for (int i = 0; i < 4; ++i)
                __builtin_amdgcn_global_load_lds((gas_t)(const void*)(gb + (size_t)i * 32 * 64),
                                                 (las_t)(void*)(lb + i * 32 * 64), 16, 0, 0);
        };
        float sexp[4][4] = {};
        const f32x4 z4 = {0.f, 0.f, 0.f, 0.f};
        stage(0, t0);
        stage(1, t0 + 1);
        const int sA = (cl & 7);
#pragma unroll 1
        for (int it = 0; it < OUT1_IT; ++it) {
            if (it == OUT1_IT - 1) {
                asm volatile("s_waitcnt vmcnt(0)" ::: "memory");   // last tile: drain
            } else {
                asm volatile("s_waitcnt vmcnt(4)" ::: "memory");   // tile it landed; it+1 in flight
            }
            __builtin_amdgcn_s_barrier();
            if (it + 2 < OUT1_IT) stage((it + 2) % 3, t0 + it + 2);
            const unsigned short* Bl = smem[it % 3];
#pragma unroll
            for (int ni = 0; ni < 4; ++ni) {
                const unsigned short* br = Bl + (wc * 64 + ni * 16 + cl) * 64;
                s16x8 b0 = *reinterpret_cast<const s16x8*>(br + (g ^ sA) * 8);
                s16x8 b1 = *reinterpret_cast<const s16x8*>(br + ((4 + g) ^ sA) * 8);
                f32x4 acc[4];
#pragma unroll
                for (int mi = 0; mi < 4; ++mi)
                    acc[mi] = mfma16(a[mi][0], b0, z4);
#pragma unroll
                for (int mi = 0; mi < 4; ++mi)
                    acc[mi] = mfma16(a[mi][1], b1, acc[mi]);
#pragma unroll
                for (int mi = 0; mi < 4; ++mi)
#pragma unroll
                    for (int r = 0; r < 4; ++r)
                        sexp[mi][r] += __builtin_amdgcn_exp2f(acc[mi][r]);
            }
        }
#pragma unroll
        for (int mi = 0; mi < 4; ++mi)
#pragma unroll
            for (int r = 0; r < 4; ++r) {
                float s = sexp[mi][r];
                s += __shfl_xor(s, 1, 64);
                s += __shfl_xor(s, 2, 64);
                s += __shfl_xor(s, 4, 64);
                s += __shfl_xor(s, 8, 64);
                if (cl == 0)
                    p1[(size_t)(yb * 2 + wc) * NROWS + row0 + mi * 16 + g * 4 + r] = s;
            }
        return;
    }
    // ================= dots: per-row target / routing logits =================
    bid -= 2016;
    int n = (bid * 256 + tid) >> 6;
    int tch = tc[n], tc0 = tc[2048 + n], tc1 = tc[4096 + n];
    const unsigned short* xr = xb + (size_t)n * 1024 + lane * 16;
    s16x8 x0 = *reinterpret_cast<const s16x8*>(xr);
    s16x8 x1 = *reinterpret_cast<const s16x8*>(xr + 8);
    const float* wh = headW + (size_t)tch * 1024 + lane * 16;
    const float* wa = headW + (size_t)2000 * 1024 + lane * 16;
    const float* wb = headW + (size_t)2001 * 1024 + lane * 16;
    float dh = 0.f, da = 0.f, db = 0.f;
#pragma unroll
    for (int i = 0; i < 8; ++i) {
        float xv = bf2f((unsigned short)x0[i]);
        dh += xv * wh[i]; da += xv * wa[i]; db += xv * wb[i];
    }
#pragma unroll
    for (int i = 0; i < 8; ++i) {
        float xv = bf2f((unsigned short)x1[i]);
        dh += xv * wh[8 + i]; da += xv * wa[8 + i]; db += xv * wb[8 + i];
    }
    ushort4 h0v = *reinterpret_cast<const ushort4*>(h01 + (size_t)n * 320 + lane * 4);
    float4 w0v = *reinterpret_cast<const float4*>(o0w + (size_t)tc0 * 256 + lane * 4);
    float d2 = bf2f(h0v.x) * w0v.x + bf2f(h0v.y) * w0v.y +
               bf2f(h0v.z) * w0v.z + bf2f(h0v.w) * w0v.w;
    float d3 = bf2f(h01[(size_t)n * 320 + 256 + lane]) * o1w[(size_t)tc1 * 64 + lane];
#pragma unroll
    for (int m = 1; m < 64; m <<= 1) {
        dh += __shfl_xor(dh, m, 64);
        da += __shfl_xor(da, m, 64);
        db += __shfl_xor(db, m, 64);
        d2 += __shfl_xor(d2, m, 64);
        d3 += __shfl_xor(d3, m, 64);
    }
    if (lane == 0) {
        tgh[n] = dh + hb[tch];
        r0[n] = da + hb[2000];
        r1[n] = db + hb[2001];
        tg0[n] = d2;
        tg1[n] = d3;
    }
}

// ---------------- finalize + fused deterministic loss ----------------
__global__ void k_finalize(const float* __restrict__ ph, const float* __restrict__ p0,
                           const float* __restrict__ p1, const float* __restrict__ tgh,
                           const float* __restrict__ r0, const float* __restrict__ r1,
                           const float* __restrict__ tg0, const float* __restrict__ tg1,
                           const int* __restrict__ tgt, float* __restrict__ outv,
                           unsigned long long* __restrict__ lossacc,
                           unsigned int* __restrict__ ticket) {
    int n = blockIdx.x * 128 + threadIdx.x;   // 16 blocks x 128
    float sh = 0.f, s0 = 0.f, s1 = 0.f;
    for (int s = 0; s < 64; ++s) sh += ph[(size_t)s * NROWS + n];
    for (int s = 0; s < 126; ++s) s0 += p0[(size_t)s * NROWS + n];
    for (int s = 0; s < 126; ++s) s1 += p1[(size_t)s * NROWS + n];
    s0 -= 64.f;   // zero-weight pad cols contribute exp2(0)=1 each
    s1 -= 63.f;
    float lh = __logf(sh), l0 = __logf(s0), l1 = __logf(s1);
    int t = tgt[n];
    float o;
    if (t < 2000) o = tgh[n] - lh;
    else if (t < 10000) o = (r0[n] - lh) + (tg0[n] - l0);
    else o = (r1[n] - lh) + (tg1[n] - l1);
    outv[n] = o;
    __shared__ float red[128];
    red[threadIdx.x] = o;
    __syncthreads();
    for (int s = 64; s > 0; s >>= 1) {
        if (threadIdx.x < s) red[threadIdx.x] += red[threadIdx.x + s];
        __syncthreads();
    }
    if (threadIdx.x == 0) {
        long long fx = __double2ll_rn((double)red[0] * 1048576.0);   // 2^20 fixed point
        atomicAdd(lossacc, (unsigned long long)fx);
        __threadfence();
        unsigned int tk = atomicAdd(ticket, 1u);
        if (tk == 15u) {
            unsigned long long v = atomicAdd(lossacc, 0ull);
            outv[NROWS] = (float)(-((double)(long long)v / 1048576.0) / 2048.0);
        }
    }
}

extern "C" void kernel_launch(void* const* d_in, const int* in_sizes, int n_in,
                              void* d_out, int out_size, void* d_ws, size_t ws_size,
                              hipStream_t stream) {
    const int* targets   = (const int*)d_in[0];
    const float* lhs     = (const float*)d_in[1];
    const int* idx       = (const int*)d_in[3];
    const float* head_W  = (const float*)d_in[4];
    const float* head_b  = (const float*)d_in[5];
    const float* proj0_W = (const float*)d_in[6];
    const float* out0_W  = (const float*)d_in[7];
    const float* proj1_W = (const float*)d_in[8];
    const float* out1_W  = (const float*)d_in[9];

    char* ws = (char*)d_ws;
    size_t off = 0;
    auto alloc = [&](size_t bytes) -> void* {
        void* p = ws + off;
        off += (bytes + 255) & ~(size_t)255;
        return p;
    };

    unsigned short* xb   = (unsigned short*)alloc((size_t)2048 * 1024 * 2);
    unsigned short* wB   = (unsigned short*)alloc((size_t)2432 * 1024 * 2);
    unsigned short* hWb  = wB;
    unsigned short* pW01 = wB + (size_t)2048 * 1024;
    unsigned short* o0Wb = (unsigned short*)alloc((size_t)8064 * 256 * 2);
    unsigned short* o1Wb = (unsigned short*)alloc((size_t)40320 * 64 * 2);
    unsigned short* h01  = (unsigned short*)alloc((size_t)2048 * 320 * 2);
    float* ph  = (float*)alloc((size_t)64 * 2048 * 4);
    float* p0  = (float*)alloc((size_t)126 * 2048 * 4);
    float* p1  = (float*)alloc((size_t)126 * 2048 * 4);
    float* tgh = (float*)alloc(2048 * 4);
    float* r0  = (float*)alloc(2048 * 4);
    float* r1  = (float*)alloc(2048 * 4);
    float* tg0 = (float*)alloc(2048 * 4);
    float* tg1 = (float*)alloc(2048 * 4);
    int*   tc  = (int*)alloc(3 * 2048 * 4);
    float* bias_s = (float*)alloc(2048 * 4);
    unsigned long long* lossacc = (unsigned long long*)alloc(8);
    unsigned int* ticket = (unsigned int*)alloc(4);

    // merged gather + convert + prep (+ counter resets)
    k_prologue<<<9024, 256, 0, stream>>>(lhs, idx, head_W, proj0_W, proj1_W, out0_W, out1_W,
                                         head_b, targets,
                                         xb, hWb, pW01, o0Wb, o1Wb, bias_s, tc,
                                         lossacc, ticket);

    // head (y<16: fused exp2-sum, 64 strips of 32) + proj (y>=16: store h01),
    // XCD-swizzled 1D grid (608 = 8*76)
    k_mm<16><<<608, 256, 0, stream>>>(
        xb, 1024, wB, 1024, bias_s, ph, h01, 320, 320, 16);

    // merged tail: out0 (1008, 128x128) | out1 (1008, 3-buf vmcnt(4)) | dots (512)
    k_tail<<<2528, 256, 0, stream>>>(h01, o0Wb, o1Wb, xb, head_W, head_b, out0_W, out1_W,
                                     tc, p0, p1, tgh, r0, r1, tg0, tg1);

    float* outv = (float*)d_out;
    k_finalize<<<16, 128, 0, stream>>>(ph, p0, p1, tgh, r0, r1, tg0, tg1, targets,
                                       outv, lossacc, ticket);
}

// Round 22
// 85.960 us; speedup vs baseline: 1.0085x; 1.0085x over previous
//
#include <hip/hip_runtime.h>
#include <hip/hip_bf16.h>

#define NROWS 2048
#define L2E 1.4426950408889634f

typedef float f32x4 __attribute__((ext_vector_type(4)));
typedef __bf16 bf16x8 __attribute__((ext_vector_type(8)));
typedef short s16x8 __attribute__((ext_vector_type(8)));

typedef const __attribute__((address_space(1))) unsigned int* gas_t;
typedef __attribute__((address_space(3))) unsigned int* las_t;

__device__ __forceinline__ unsigned short f2bf(float f) {
    unsigned int u = __float_as_uint(f);
    unsigned int r = (u + 0x7FFFu + ((u >> 16) & 1u)) >> 16;
    return (unsigned short)r;
}
__device__ __forceinline__ float bf2f(unsigned short u) {
    return __uint_as_float((unsigned int)u << 16);
}
__device__ __forceinline__ f32x4 mfma16(s16x8 a, s16x8 b, f32x4 c) {
    return __builtin_amdgcn_mfma_f32_16x16x32_bf16(
        __builtin_bit_cast(bf16x8, a), __builtin_bit_cast(bf16x8, b), c, 0, 0, 0);
}

// ---------------- merged prologue: gather x | convert weights | prep ----------------
__global__ void k_prologue(const float* __restrict__ lhs, const int* __restrict__ idx,
                           const float* __restrict__ hw, const float* __restrict__ p0w,
                           const float* __restrict__ p1w, const float* __restrict__ o0w,
                           const float* __restrict__ o1w, const float* __restrict__ hb,
                           const int* __restrict__ tgt,
                           unsigned short* __restrict__ xb, unsigned short* __restrict__ hWb,
                           unsigned short* __restrict__ pW01, unsigned short* __restrict__ o0Wb,
                           unsigned short* __restrict__ o1Wb,
                           float* __restrict__ bias_s, int* __restrict__ tc,
                           unsigned long long* __restrict__ lossacc,
                           unsigned int* __restrict__ ticket) {
    int bid = blockIdx.x;
    if (bid < 2048) {                      // ---- gather x: 2048 rows x 1024 cols bf16
        int tid = bid * 256 + threadIdx.x;
        int n = tid >> 8;
        int c = (tid & 255) << 2;
        int b = n >> 8, k = n & 255;
        int srow = idx[(b << 8) + k];
        const float4 v = *reinterpret_cast<const float4*>(
            lhs + (((size_t)b << 9) + srow) * 1024 + c);
        ushort4 o = make_ushort4(f2bf(v.x), f2bf(v.y), f2bf(v.z), f2bf(v.w));
        *reinterpret_cast<ushort4*>(xb + (size_t)n * 1024 + c) = o;
        return;
    }
    bid -= 2048;
    if (bid < 6968) {                      // ---- weight conversion (exp-weights * log2e)
        const long B0 = 2048L * 1024;
        const long B1 = B0 + 384L * 1024;
        const long B2 = B1 + 8064L * 256;
        const long B3 = B2 + 40320L * 64;
        long e = ((long)bid * 256 + threadIdx.x) * 4;
        if (e >= B3) return;
        const float* src; unsigned short* dst; long rows; int colshift; long base;
        float sc;
        if (e < B0)      { base = 0;  src = hw;  dst = hWb;  rows = 2002;  colshift = 10; sc = L2E; }
        else if (e < B1) {
            long l = e - B0;
            long row = l >> 10;
            unsigned short* d = pW01 + l;
            ushort4 o;
            if (row < 256) {
                float4 v = *reinterpret_cast<const float4*>(p0w + l);
                o = make_ushort4(f2bf(v.x), f2bf(v.y), f2bf(v.z), f2bf(v.w));
            } else if (row < 320) {
                float4 v = *reinterpret_cast<const float4*>(p1w + (l - 256L * 1024));
                o = make_ushort4(f2bf(v.x), f2bf(v.y), f2bf(v.z), f2bf(v.w));
            } else {
                o = make_ushort4(0, 0, 0, 0);
            }
            *reinterpret_cast<ushort4*>(d) = o;
            return;
        }
        else if (e < B2) { base = B1; src = o0w; dst = o0Wb; rows = 8000;  colshift = 8; sc = L2E; }
        else             { base = B2; src = o1w; dst = o1Wb; rows = 40257; colshift = 6; sc = L2E; }
        long l = e - base;
        long row = l >> colshift;
        ushort4 o;
        if (row < rows) {
            float4 v = *reinterpret_cast<const float4*>(src + l);
            o = make_ushort4(f2bf(v.x * sc), f2bf(v.y * sc), f2bf(v.z * sc), f2bf(v.w * sc));
        } else {
            o = make_ushort4(0, 0, 0, 0);
        }
        *reinterpret_cast<ushort4*>(dst + l) = o;
        return;
    }
    bid -= 6968;                           // ---- prep (8 blocks)
    int n = bid * 256 + threadIdx.x;
    if (n >= 2048) return;
    if (n == 0) { *lossacc = 0ull; *ticket = 0u; }
    bias_s[n] = (n < 2002) ? hb[n] * L2E : -1e30f;
    int t = tgt[n];
    tc[n] = min(t, 1999);
    tc[2048 + n] = min(max(t - 2000, 0), 7999);
    tc[4096 + n] = min(max(t - 10000, 0), 40256);
}

// ------- head+proj: 64x128-tile GEMM, BK=64, dbuf + XOR swizzle, XCD-swizzled -------
template <int NT>
__global__ __launch_bounds__(256)
void k_mm(const unsigned short* __restrict__ A, int lda,
          const unsigned short* __restrict__ B, int ldb,
          const float* __restrict__ bias, float* __restrict__ partial,
          unsigned short* __restrict__ hout, int hstride, int hcols, int fsplit) {
    __shared__ unsigned short As[2][64 * 64];
    __shared__ unsigned short Bs[2][128 * 64];
    const int tid = threadIdx.x;
    const int lane = tid & 63, wid = tid >> 6;
    const int wc = wid;
    const int g = lane >> 4, cl = lane & 15;
    int raw = (int)blockIdx.x;
    int bid = (raw & 7) * 76 + (raw >> 3);           // XCD swizzle (608 = 8*76)
    const int bx = bid & 31, by = bid >> 5;
    const int row0 = bx * 64;
    const int col0 = by * 128;

    const int sr = wid * 8 + (lane >> 3);
    const int swz = ((lane & 7) ^ (lane >> 3)) * 8;
    const unsigned short* Ab = A + (size_t)(row0 + sr) * lda + swz;
    const unsigned short* Bb = B + (size_t)(col0 + sr) * ldb + swz;

    auto stage = [&](int buf, int kt) {
        unsigned short* la = &As[buf][wid * 8 * 64];
        unsigned short* lb = &Bs[buf][wid * 8 * 64];
#pragma unroll
        for (int i = 0; i < 2; ++i)
            __builtin_amdgcn_global_load_lds((gas_t)(const void*)(Ab + kt + (size_t)i * 32 * lda),
                                             (las_t)(void*)(la + i * 32 * 64), 16, 0, 0);
#pragma unroll
        for (int i = 0; i < 4; ++i)
            __builtin_amdgcn_global_load_lds((gas_t)(const void*)(Bb + kt + (size_t)i * 32 * ldb),
                                             (las_t)(void*)(lb + i * 32 * 64), 16, 0, 0);
    };

    f32x4 acc[4][2] = {};
    stage(0, 0);
    asm volatile("s_waitcnt vmcnt(0)" ::: "memory");
    __builtin_amdgcn_s_barrier();
    const int sA = (cl & 7);
    for (int t = 0; t < NT; ++t) {
        if (t + 1 < NT) stage((t + 1) & 1, (t + 1) * 64);
        const unsigned short* Al = &As[t & 1][cl * 64];
        const unsigned short* Bl = &Bs[t & 1][(wc * 32 + cl) * 64];
#pragma unroll
        for (int kk2 = 0; kk2 < 2; ++kk2) {
            const int slot = ((kk2 * 4 + g) ^ sA) * 8;
            s16x8 a[4], b[2];
#pragma unroll
            for (int mi = 0; mi < 4; ++mi)
                a[mi] = *reinterpret_cast<const s16x8*>(Al + mi * 16 * 64 + slot);
#pragma unroll
            for (int ni = 0; ni < 2; ++ni)
                b[ni] = *reinterpret_cast<const s16x8*>(Bl + ni * 16 * 64 + slot);
#pragma unroll
            for (int mi = 0; mi < 4; ++mi)
#pragma unroll
                for (int ni = 0; ni < 2; ++ni)
                    acc[mi][ni] = mfma16(a[mi], b[ni], acc[mi][ni]);
        }
        if (t + 1 < NT) {
            asm volatile("s_waitcnt vmcnt(0)" ::: "memory");
            __builtin_amdgcn_s_barrier();
        }
    }

    if (by >= fsplit) {
        int c0 = col0 - fsplit * 128;
#pragma unroll
        for (int mi = 0; mi < 4; ++mi)
#pragma unroll
            for (int ni = 0; ni < 2; ++ni) {
                int col = c0 + wc * 32 + ni * 16 + cl;
                if (col < hcols) {
#pragma unroll
                    for (int r = 0; r < 4; ++r) {
                        int row = row0 + mi * 16 + g * 4 + r;
                        hout[(size_t)row * hstride + col] = f2bf(acc[mi][ni][r]);
                    }
                }
            }
    } else {
        float bv0 = bias[col0 + wc * 32 + cl];
        float bv1 = bias[col0 + wc * 32 + 16 + cl];
        int strip = by * 4 + wc;
#pragma unroll
        for (int mi = 0; mi < 4; ++mi)
#pragma unroll
            for (int r = 0; r < 4; ++r) {
                float s = __builtin_amdgcn_exp2f(acc[mi][0][r] + bv0)
                        + __builtin_amdgcn_exp2f(acc[mi][1][r] + bv1);
                s += __shfl_xor(s, 1, 64);
                s += __shfl_xor(s, 2, 64);
                s += __shfl_xor(s, 4, 64);
                s += __shfl_xor(s, 8, 64);
                if (cl == 0)
                    partial[(size_t)strip * NROWS + row0 + mi * 16 + g * 4 + r] = s;
            }
    }
}

// --- merged tail: out0 (1008, 128x128) | out1 (1008) | dots (512), per-segment XCD swizzle ---
#define OUT1_IT 5
__global__ __launch_bounds__(256)
void k_tail(const unsigned short* __restrict__ h01, const unsigned short* __restrict__ o0Wb,
            const unsigned short* __restrict__ o1Wb, const unsigned short* __restrict__ xb,
            const float* __restrict__ headW, const float* __restrict__ hb,
            const float* __restrict__ o0w, const float* __restrict__ o1w,
            const int* __restrict__ tc,
            float* __restrict__ p0, float* __restrict__ p1,
            float* __restrict__ tgh, float* __restrict__ r0, float* __restrict__ r1,
            float* __restrict__ tg0, float* __restrict__ tg1) {
    __shared__ unsigned short smem[4][128 * 64];
    const int tid = threadIdx.x;
    const int lane = tid & 63, wid = tid >> 6;
    const int wr = wid >> 1, wc = wid & 1;
    const int g = lane >> 4, cl = lane & 15;
    int raw = (int)blockIdx.x;
    int bid;
    if (raw < 1008)      bid = (raw & 7) * 126 + (raw >> 3);
    else if (raw < 2016) { int b = raw - 1008; bid = 1008 + (b & 7) * 126 + (b >> 3); }
    else                 { int b = raw - 2016; bid = 2016 + (b & 7) * 64 + (b >> 3); }

    if (bid < 1008) {
        // ================= out0: 2048 x 8064, K=256, fused exp2-sum =================
        const int row0 = (bid & 15) * 128;
        const int col0 = (bid >> 4) * 128;
        const int sr = wid * 8 + (lane >> 3);
        const int swz = ((lane & 7) ^ (lane >> 3)) * 8;
        const unsigned short* Ab = h01 + (size_t)(row0 + sr) * 320 + swz;
        const unsigned short* Bb = o0Wb + (size_t)(col0 + sr) * 256 + swz;
        auto stage = [&](int buf, int kt) {
            unsigned short* la = &smem[buf][wid * 8 * 64];
            unsigned short* lb = &smem[2 + buf][wid * 8 * 64];
#pragma unroll
            for (int i = 0; i < 4; ++i) {
                __builtin_amdgcn_global_load_lds((gas_t)(const void*)(Ab + kt + (size_t)i * 32 * 320),
                                                 (las_t)(void*)(la + i * 32 * 64), 16, 0, 0);
                __builtin_amdgcn_global_load_lds((gas_t)(const void*)(Bb + kt + (size_t)i * 32 * 256),
                                                 (las_t)(void*)(lb + i * 32 * 64), 16, 0, 0);
            }
        };
        f32x4 acc[4][4] = {};
        stage(0, 0);
        asm volatile("s_waitcnt vmcnt(0)" ::: "memory");
        __builtin_amdgcn_s_barrier();
        const int sA = (cl & 7);
        for (int t = 0; t < 4; ++t) {
            if (t < 3) stage((t + 1) & 1, (t + 1) * 64);
            const unsigned short* Al = &smem[t & 1][(wr * 64 + cl) * 64];
            const unsigned short* Bl = &smem[2 + (t & 1)][(wc * 64 + cl) * 64];
#pragma unroll
            for (int kk2 = 0; kk2 < 2; ++kk2) {
                const int slot = ((kk2 * 4 + g) ^ sA) * 8;
                s16x8 a[4], b[4];
#pragma unroll
                for (int mi = 0; mi < 4; ++mi)
                    a[mi] = *reinterpret_cast<const s16x8*>(Al + mi * 16 * 64 + slot);
#pragma unroll
                for (int ni = 0; ni < 4; ++ni)
                    b[ni] = *reinterpret_cast<const s16x8*>(Bl + ni * 16 * 64 + slot);
#pragma unroll
                for (int mi = 0; mi < 4; ++mi)
#pragma unroll
                    for (int ni = 0; ni < 4; ++ni)
                        acc[mi][ni] = mfma16(a[mi], b[ni], acc[mi][ni]);
            }
            if (t < 3) {
                asm volatile("s_waitcnt vmcnt(0)" ::: "memory");
                __builtin_amdgcn_s_barrier();
            }
        }
        int strip = (bid >> 4) * 2 + wc;
#pragma unroll
        for (int mi = 0; mi < 4; ++mi)
#pragma unroll
            for (int r = 0; r < 4; ++r) {
                float s = 0.f;
#pragma unroll
                for (int ni = 0; ni < 4; ++ni)
                    s += __builtin_amdgcn_exp2f(acc[mi][ni][r]);
                s += __shfl_xor(s, 1, 64);
                s += __shfl_xor(s, 2, 64);
                s += __shfl_xor(s, 4, 64);
                s += __shfl_xor(s, 8, 64);
                if (cl == 0)
                    p0[(size_t)strip * NROWS + row0 + wr * 64 + mi * 16 + g * 4 + r] = s;
            }
        return;
    }
    if (bid < 2016) {
        // ================= out1: 2048 x 40320, K=64, 5 col-tiles/block =================
        bid -= 1008;
        const int row0 = (bid & 15) * 128 + wr * 64;
        const int yb = bid >> 4;
        const int t0 = yb * OUT1_IT;
        s16x8 a[4][2];
#pragma unroll
        for (int mi = 0; mi < 4; ++mi)
#pragma unroll
            for (int kk = 0; kk < 2; ++kk)
                a[mi][kk] = *reinterpret_cast<const s16x8*>(
                    h01 + (size_t)(row0 + mi * 16 + cl) * 320 + 256 + kk * 32 + g * 8);
        const int sr = wid * 8 + (lane >> 3);
        const int swz = ((lane & 7) ^ (lane >> 3)) * 8;
        auto stage = [&](int buf, int tile) {
            const unsigned short* gb = o1Wb + ((size_t)tile * 128 + sr) * 64 + swz;
            unsigned short* lb = &smem[buf][wid * 8 * 64];
#pragma unroll
            for (int i = 0; i < 4; ++i)
                __builtin_amdgcn_global_load_lds((gas_t)(const void*)(gb + (size_t)i * 32 * 64),
                                                 (las_t)(void*)(lb + i * 32 * 64), 16, 0, 0);
        };
        float sexp[4][4] = {};
        const f32x4 z4 = {0.f, 0.f, 0.f, 0.f};
        stage(0, t0);
        asm volatile("s_waitcnt vmcnt(0)" ::: "memory");
        __builtin_amdgcn_s_barrier();
        int buf = 0;
        const int sA = (cl & 7);
#pragma unroll 1
        for (int it = 0; it < OUT1_IT; ++it) {
            if (it + 1 < OUT1_IT) stage(buf ^ 1, t0 + it + 1);
            const unsigned short* Bl = smem[buf];
#pragma unroll
            for (int ni = 0; ni < 4; ++ni) {
                const unsigned short* br = Bl + (wc * 64 + ni * 16 + cl) * 64;
                s16x8 b0 = *reinterpret_cast<const s16x8*>(br + (g ^ sA) * 8);
                s16x8 b1 = *reinterpret_cast<const s16x8*>(br + ((4 + g) ^ sA) * 8);
                f32x4 acc[4];
#pragma unroll
                for (int mi = 0; mi < 4; ++mi)
                    acc[mi] = mfma16(a[mi][0], b0, z4);
#pragma unroll
                for (int mi = 0; mi < 4; ++mi)
                    acc[mi] = mfma16(a[mi][1], b1, acc[mi]);
#pragma unroll
                for (int mi = 0; mi < 4; ++mi)
#pragma unroll
                    for (int r = 0; r < 4; ++r)
                        sexp[mi][r] += __builtin_amdgcn_exp2f(acc[mi][r]);
            }
            if (it + 1 < OUT1_IT) {
                asm volatile("s_waitcnt vmcnt(0)" ::: "memory");
                __builtin_amdgcn_s_barrier();
                buf ^= 1;
            }
        }
#pragma unroll
        for (int mi = 0; mi < 4; ++mi)
#pragma unroll
            for (int r = 0; r < 4; ++r) {
                float s = sexp[mi][r];
                s += __shfl_xor(s, 1, 64);
                s += __shfl_xor(s, 2, 64);
                s += __shfl_xor(s, 4, 64);
                s += __shfl_xor(s, 8, 64);
                if (cl == 0)
                    p1[(size_t)(yb * 2 + wc) * NROWS + row0 + mi * 16 + g * 4 + r] = s;
            }
        return;
    }
    // ================= dots: per-row target / routing logits =================
    bid -= 2016;
    int n = (bid * 256 + tid) >> 6;
    int tch = tc[n], tc0 = tc[2048 + n], tc1 = tc[4096 + n];
    const unsigned short* xr = xb + (size_t)n * 1024 + lane * 16;
    s16x8 x0 = *reinterpret_cast<const s16x8*>(xr);
    s16x8 x1 = *reinterpret_cast<const s16x8*>(xr + 8);
    const float* wh = headW + (size_t)tch * 1024 + lane * 16;
    const float* wa = headW + (size_t)2000 * 1024 + lane * 16;
    const float* wb = headW + (size_t)2001 * 1024 + lane * 16;
    float dh = 0.f, da = 0.f, db = 0.f;
#pragma unroll
    for (int i = 0; i < 8; ++i) {
        float xv = bf2f((unsigned short)x0[i]);
        dh += xv * wh[i]; da += xv * wa[i]; db += xv * wb[i];
    }
#pragma unroll
    for (int i = 0; i < 8; ++i) {
        float xv = bf2f((unsigned short)x1[i]);
        dh += xv * wh[8 + i]; da += xv * wa[8 + i]; db += xv * wb[8 + i];
    }
    ushort4 h0v = *reinterpret_cast<const ushort4*>(h01 + (size_t)n * 320 + lane * 4);
    float4 w0v = *reinterpret_cast<const float4*>(o0w + (size_t)tc0 * 256 + lane * 4);
    float d2 = bf2f(h0v.x) * w0v.x + bf2f(h0v.y) * w0v.y +
               bf2f(h0v.z) * w0v.z + bf2f(h0v.w) * w0v.w;
    float d3 = bf2f(h01[(size_t)n * 320 + 256 + lane]) * o1w[(size_t)tc1 * 64 + lane];
#pragma unroll
    for (int m = 1; m < 64; m <<= 1) {
        dh += __shfl_xor(dh, m, 64);
        da += __shfl_xor(da, m, 64);
        db += __shfl_xor(db, m, 64);
        d2 += __shfl_xor(d2, m, 64);
        d3 += __shfl_xor(d3, m, 64);
    }
    if (lane == 0) {
        tgh[n] = dh + hb[tch];
        r0[n] = da + hb[2000];
        r1[n] = db + hb[2001];
        tg0[n] = d2;
        tg1[n] = d3;
    }
}

// ---------------- finalize + fused deterministic loss ----------------
__global__ void k_finalize(const float* __restrict__ ph, const float* __restrict__ p0,
                           const float* __restrict__ p1, const float* __restrict__ tgh,
                           const float* __restrict__ r0, const float* __restrict__ r1,
                           const float* __restrict__ tg0, const float* __restrict__ tg1,
                           const int* __restrict__ tgt, float* __restrict__ outv,
                           unsigned long long* __restrict__ lossacc,
                           unsigned int* __restrict__ ticket) {
    int n = blockIdx.x * 128 + threadIdx.x;   // 16 blocks x 128
    float sh = 0.f, s0 = 0.f, s1 = 0.f;
    for (int s = 0; s < 64; ++s) sh += ph[(size_t)s * NROWS + n];
    for (int s = 0; s < 126; ++s) s0 += p0[(size_t)s * NROWS + n];
    for (int s = 0; s < 126; ++s) s1 += p1[(size_t)s * NROWS + n];
    s0 -= 64.f;   // zero-weight pad cols contribute exp2(0)=1 each
    s1 -= 63.f;
    float lh = __logf(sh), l0 = __logf(s0), l1 = __logf(s1);
    int t = tgt[n];
    float o;
    if (t < 2000) o = tgh[n] - lh;
    else if (t < 10000) o = (r0[n] - lh) + (tg0[n] - l0);
    else o = (r1[n] - lh) + (tg1[n] - l1);
    outv[n] = o;
    __shared__ float red[128];
    red[threadIdx.x] = o;
    __syncthreads();
    for (int s = 64; s > 0; s >>= 1) {
        if (threadIdx.x < s) red[threadIdx.x] += red[threadIdx.x + s];
        __syncthreads();
    }
    if (threadIdx.x == 0) {
        long long fx = __double2ll_rn((double)red[0] * 1048576.0);   // 2^20 fixed point
        atomicAdd(lossacc, (unsigned long long)fx);
        __threadfence();
        unsigned int tk = atomicAdd(ticket, 1u);
        if (tk == 15u) {
            unsigned long long v = atomicAdd(lossacc, 0ull);
            outv[NROWS] = (float)(-((double)(long long)v / 1048576.0) / 2048.0);
        }
    }
}

extern "C" void kernel_launch(void* const* d_in, const int* in_sizes, int n_in,
                              void* d_out, int out_size, void* d_ws, size_t ws_size,
                              hipStream_t stream) {
    const int* targets   = (const int*)d_in[0];
    const float* lhs     = (const float*)d_in[1];
    const int* idx       = (const int*)d_in[3];
    const float* head_W  = (const float*)d_in[4];
    const float* head_b  = (const float*)d_in[5];
    const float* proj0_W = (const float*)d_in[6];
    const float* out0_W  = (const float*)d_in[7];
    const float* proj1_W = (const float*)d_in[8];
    const float* out1_W  = (const float*)d_in[9];

    char* ws = (char*)d_ws;
    size_t off = 0;
    auto alloc = [&](size_t bytes) -> void* {
        void* p = ws + off;
        off += (bytes + 255) & ~(size_t)255;
        return p;
    };

    unsigned short* xb   = (unsigned short*)alloc((size_t)2048 * 1024 * 2);
    unsigned short* wB   = (unsigned short*)alloc((size_t)2432 * 1024 * 2);
    unsigned short* hWb  = wB;
    unsigned short* pW01 = wB + (size_t)2048 * 1024;
    unsigned short* o0Wb = (unsigned short*)alloc((size_t)8064 * 256 * 2);
    unsigned short* o1Wb = (unsigned short*)alloc((size_t)40320 * 64 * 2);
    unsigned short* h01  = (unsigned short*)alloc((size_t)2048 * 320 * 2);
    float* ph  = (float*)alloc((size_t)64 * 2048 * 4);
    float* p0  = (float*)alloc((size_t)126 * 2048 * 4);
    float* p1  = (float*)alloc((size_t)126 * 2048 * 4);
    float* tgh = (float*)alloc(2048 * 4);
    float* r0  = (float*)alloc(2048 * 4);
    float* r1  = (float*)alloc(2048 * 4);
    float* tg0 = (float*)alloc(2048 * 4);
    float* tg1 = (float*)alloc(2048 * 4);
    int*   tc  = (int*)alloc(3 * 2048 * 4);
    float* bias_s = (float*)alloc(2048 * 4);
    unsigned long long* lossacc = (unsigned long long*)alloc(8);
    unsigned int* ticket = (unsigned int*)alloc(4);

    // merged gather + convert + prep (+ counter resets)
    k_prologue<<<9024, 256, 0, stream>>>(lhs, idx, head_W, proj0_W, proj1_W, out0_W, out1_W,
                                         head_b, targets,
                                         xb, hWb, pW01, o0Wb, o1Wb, bias_s, tc,
                                         lossacc, ticket);

    // head (y<16: fused exp2-sum, 64 strips of 32) + proj (y>=16: store h01),
    // XCD-swizzled 1D grid (608 = 8*76)
    k_mm<16><<<608, 256, 0, stream>>>(
        xb, 1024, wB, 1024, bias_s, ph, h01, 320, 320, 16);

    // merged tail: out0 (1008, 128x128) | out1 (1008) | dots (512), per-segment swizzle
    k_tail<<<2528, 256, 0, stream>>>(h01, o0Wb, o1Wb, xb, head_W, head_b, out0_W, out1_W,
                                     tc, p0, p1, tgh, r0, r1, tg0, tg1);

    float* outv = (float*)d_out;
    k_finalize<<<16, 128, 0, stream>>>(ph, p0, p1, tgh, r0, r1, tg0, tg1, targets,
                                       outv, lossacc, ticket);
}